// Round 9
// baseline (143.111 us; speedup 1.0000x reference)
//
#include <hip/hip_runtime.h>
#include <float.h>
#include <math.h>

// AdvancedLossFunction: total = 1.0*occ + 0.1*smooth + 0.01*sparse + 0.1*cons
// 3 dispatches. 3-NN via branchless packed-key brute force:
//   key(i,j) = float_bits(d2(i,j)) with low 14 mantissa bits replaced by j.
//   Ordering by key == ordering by d2 at 2^-9 relative resolution; payload
//   carries the neighbor index (exact pred gathered in merge).
//   Top-4 keys per i kept with fmin + 3x v_med3_f32 — ~10 flat VALU ops/pair,
//   no branches, no self-check (self d2 ~ 0 is always the minimum key).
// R8 lesson: CHUNKS=64 (grid 1024) = 16 waves/CU starved latency hiding;
// back to grid 2048 (R4's 85%-VALUBusy shape). R7: flat > __any-gated.
// R6: no contended atomics anywhere.

constexpr int   N_ = 16384;
constexpr int   F_ = 64;
constexpr float OCC_W = 1.0f, SMOOTH_W = 0.1f, SPARSE_W = 0.01f, CONS_W = 0.1f;
constexpr float EPS_ = 1e-7f;

// ws layout:
//   0      : float4 part[1024]        (occ, cons, sparse, smooth per merge-block)
//   16384  : float4 cand[CHUNKS][N]   (top-4 packed keys per (chunk, i))

__device__ __forceinline__ void ins4f(float t, float& b0, float& b1, float& b2, float& b3) {
  // maintains b0<=b1<=b2<=b3; med3(a,b,t) with a<=b == clamp(t,a,b) == sorted insert
  float n0 = fminf(b0, t);
  float n1 = __builtin_amdgcn_fmed3f(b0, b1, t);
  float n2 = __builtin_amdgcn_fmed3f(b1, b2, t);
  float n3 = __builtin_amdgcn_fmed3f(b2, b3, t);
  b0 = n0; b1 = n1; b2 = n2; b3 = n3;
}

template <int CHUNKS>
__global__ __launch_bounds__(256) void knn_kernel(const float* __restrict__ pts,
                                                  float4* __restrict__ cand) {
  constexpr int CHUNK   = N_ / CHUNKS;             // 128 at CHUNKS=128
  constexpr int TILE    = CHUNK;
  constexpr int ITEMS   = 4;
  constexpr int IPG     = 1024;
  constexpr int IGROUPS = N_ / IPG;                // 16
  int igrp  = blockIdx.x % IGROUPS;
  int chunk = blockIdx.x / IGROUPS;
  int j0    = chunk * CHUNK;

  __shared__ float4 tile[TILE];                    // (-2x,-2y,-2z,|q|^2)

  for (int t = threadIdx.x; t < TILE; t += 256) {
    int j = j0 + t;
    float x = pts[3 * j], y = pts[3 * j + 1], z = pts[3 * j + 2];
    tile[t] = make_float4(-2.f * x, -2.f * y, -2.f * z, fmaf(x, x, fmaf(y, y, z * z)));
  }

  float xi[ITEMS], yi[ITEMS], zi[ITEMS], sqi[ITEMS];
  float b0[ITEMS], b1[ITEMS], b2[ITEMS], b3[ITEMS];
#pragma unroll
  for (int k = 0; k < ITEMS; ++k) {
    int i = igrp * IPG + threadIdx.x + k * 256;
    float x = pts[3 * i], y = pts[3 * i + 1], z = pts[3 * i + 2];
    xi[k] = x; yi[k] = y; zi[k] = z;
    sqi[k] = fmaf(x, x, fmaf(y, y, z * z));
    b0[k] = b1[k] = b2[k] = b3[k] = FLT_MAX;
  }
  __syncthreads();

#pragma unroll 4
  for (int jj = 0; jj < TILE; ++jj) {
    float4 q = tile[jj];                           // wave-uniform -> LDS broadcast
    unsigned jg = (unsigned)(j0 + jj);             // wave-uniform (SGPR) payload
#pragma unroll
    for (int k = 0; k < ITEMS; ++k) {
      float t  = fmaf(xi[k], q.x, fmaf(yi[k], q.y, fmaf(zi[k], q.z, q.w)));  // -2p.q+|q|^2
      float d2 = t + sqi[k];                       // = |p-q|^2 (+- ulps; self ~ 0)
      float kf = __uint_as_float((__float_as_uint(d2) & 0xFFFFC000u) | jg);
      ins4f(kf, b0[k], b1[k], b2[k], b3[k]);       // ~10 flat VALU ops/pair total
    }
  }

#pragma unroll
  for (int k = 0; k < ITEMS; ++k) {
    int i = igrp * IPG + threadIdx.x + k * 256;
    cand[(size_t)chunk * N_ + i] = make_float4(b0[k], b1[k], b2[k], b3[k]);
  }
}

// grid 1024: merges per-chunk top-4s, gathers exact neighbor preds -> smoothness,
// plus all scalar reductions (feat float4s covered exactly once). float4 partial/block.
template <int CHUNKS>
__global__ __launch_bounds__(256) void merge_kernel(const float* __restrict__ pred,
                                                    const float* __restrict__ targ,
                                                    const float* __restrict__ feat,
                                                    const float4* __restrict__ cand,
                                                    float4* __restrict__ part) {
  __shared__ float4 sh[256];
  __shared__ float ws4[4][4];
  int tid = threadIdx.x;
  int i_local = tid & 15, sub = tid >> 4;          // 16 i's/block, 16 threads/i
  int i = blockIdx.x * 16 + i_local;

  float4 v = ((const float4*)feat)[blockIdx.x * 256 + tid];
  float s_sp = fabsf(v.x) + fabsf(v.y) + fabsf(v.z) + fabsf(v.w);

  constexpr int CPT = CHUNKS / 16;
  float b0 = FLT_MAX, b1 = FLT_MAX, b2 = FLT_MAX, b3 = FLT_MAX;
  for (int cc = 0; cc < CPT; ++cc) {
    float4 q = cand[(size_t)(sub * CPT + cc) * N_ + i];   // 16 consecutive i -> 256B
    ins4f(q.x, b0, b1, b2, b3);
    ins4f(q.y, b0, b1, b2, b3);
    ins4f(q.z, b0, b1, b2, b3);
    ins4f(q.w, b0, b1, b2, b3);
  }
  sh[tid] = make_float4(b0, b1, b2, b3);
  __syncthreads();
  for (int st = 8; st > 0; st >>= 1) {
    if (sub < st) {
      float4 q = sh[((sub + st) << 4) | i_local];
      ins4f(q.x, b0, b1, b2, b3);
      ins4f(q.y, b0, b1, b2, b3);
      ins4f(q.z, b0, b1, b2, b3);
      ins4f(q.w, b0, b1, b2, b3);
      sh[tid] = make_float4(b0, b1, b2, b3);
    }
    __syncthreads();
  }

  float s_occ = 0.f, s_cons = 0.f, s_sm = 0.f;
  if (sub == 0) {                                  // tid < 16: global top-4 for i
    float pi = pred[i], tg = targ[i];
    float p  = fminf(fmaxf(pi, EPS_), 1.0f - EPS_);
    s_occ = -(tg * __logf(p) + (1.0f - tg) * __logf(1.0f - p));
    float d = pi - tg;
    s_cons = d * d;
    // b0 = self (d2~0, minimum); b1..b3 = the 3 NNs; low 14 bits = neighbor index
    float p1 = pred[__float_as_uint(b1) & 0x3FFFu];     // 64KB array: L2-resident gather
    float p2 = pred[__float_as_uint(b2) & 0x3FFFu];
    float p3 = pred[__float_as_uint(b3) & 0x3FFFu];
    s_sm = fabsf(pi - p1) + fabsf(pi - p2) + fabsf(pi - p3);
  }

  for (int off = 32; off > 0; off >>= 1) {         // zeros on lanes >=16 keep sums exact
    s_sp   += __shfl_down(s_sp, off);
    s_occ  += __shfl_down(s_occ, off);
    s_cons += __shfl_down(s_cons, off);
    s_sm   += __shfl_down(s_sm, off);
  }
  if ((tid & 63) == 0) {
    int w = tid >> 6;
    ws4[w][0] = s_occ; ws4[w][1] = s_cons; ws4[w][2] = s_sp; ws4[w][3] = s_sm;
  }
  __syncthreads();
  if (tid == 0) {
    part[blockIdx.x] = make_float4(ws4[0][0] + ws4[1][0] + ws4[2][0] + ws4[3][0],
                                   ws4[0][1] + ws4[1][1] + ws4[2][1] + ws4[3][1],
                                   ws4[0][2] + ws4[1][2] + ws4[2][2] + ws4[3][2],
                                   ws4[0][3] + ws4[1][3] + ws4[2][3] + ws4[3][3]);
  }
}

__global__ __launch_bounds__(256) void finalize_kernel(const float4* __restrict__ part,
                                                       float* __restrict__ out) {
  __shared__ float ws4[4][4];
  int tid = threadIdx.x;
  float4 a = part[tid], b = part[256 + tid], c = part[512 + tid], d = part[768 + tid];
  float o  = a.x + b.x + c.x + d.x;
  float cn = a.y + b.y + c.y + d.y;
  float sp = a.z + b.z + c.z + d.z;
  float sm = a.w + b.w + c.w + d.w;
  for (int off = 32; off > 0; off >>= 1) {
    o  += __shfl_down(o, off);
    cn += __shfl_down(cn, off);
    sp += __shfl_down(sp, off);
    sm += __shfl_down(sm, off);
  }
  if ((tid & 63) == 0) {
    int w = tid >> 6;
    ws4[w][0] = o; ws4[w][1] = cn; ws4[w][2] = sp; ws4[w][3] = sm;
  }
  __syncthreads();
  if (tid == 0) {
    float occ  = ws4[0][0] + ws4[1][0] + ws4[2][0] + ws4[3][0];
    float cons = ws4[0][1] + ws4[1][1] + ws4[2][1] + ws4[3][1];
    float spar = ws4[0][2] + ws4[1][2] + ws4[2][2] + ws4[3][2];
    float smoo = ws4[0][3] + ws4[1][3] + ws4[2][3] + ws4[3][3];
    out[0] = OCC_W * (occ / (float)N_)
           + CONS_W * (cons / (float)N_)
           + SPARSE_W * (spar / (float)(N_ * F_))
           + SMOOTH_W * (smoo / (float)(N_ * 3));
  }
}

extern "C" void kernel_launch(void* const* d_in, const int* in_sizes, int n_in,
                              void* d_out, int out_size, void* d_ws, size_t ws_size,
                              hipStream_t stream) {
  const float* pred = (const float*)d_in[0];
  const float* targ = (const float*)d_in[1];
  const float* feat = (const float*)d_in[2];
  const float* pts  = (const float*)d_in[3];
  float* out = (float*)d_out;

  char*   ws   = (char*)d_ws;
  float4* part = (float4*)ws;                      // 1024 * 16B = 16 KB
  float4* cand = (float4*)(ws + 16384);

  size_t need128 = 16384 + (size_t)128 * N_ * 16;  // 33.6 MB
  size_t need64  = 16384 + (size_t)64  * N_ * 16;  // 16.8 MB
  if (ws_size >= need128) {
    knn_kernel<128><<<16 * 128, 256, 0, stream>>>(pts, cand);
    merge_kernel<128><<<1024, 256, 0, stream>>>(pred, targ, feat, cand, part);
  } else if (ws_size >= need64) {
    knn_kernel<64><<<16 * 64, 256, 0, stream>>>(pts, cand);
    merge_kernel<64><<<1024, 256, 0, stream>>>(pred, targ, feat, cand, part);
  } else {
    knn_kernel<32><<<16 * 32, 256, 0, stream>>>(pts, cand);
    merge_kernel<32><<<1024, 256, 0, stream>>>(pred, targ, feat, cand, part);
  }
  finalize_kernel<<<1, 256, 0, stream>>>(part, out);
}